// Round 1
// baseline (271.473 us; speedup 1.0000x reference)
//
#include <hip/hip_runtime.h>
#include <hip/hip_bf16.h>
#include <stdint.h>

// Problem constants (fixed shapes from reference)
#define NTOK 4096      // B*L = 4*1024
#define DDIM 768
#define HDIM 1536
#define NEXP 6
#define NTYPE 32
#define PADROWS 4224   // NTOK + 128 padding for partial-tile staging reads

typedef __bf16 bf16x8 __attribute__((ext_vector_type(8)));
typedef float f32x4 __attribute__((ext_vector_type(4)));

static __device__ __forceinline__ unsigned short f2bf(float f) {
  union { float f; unsigned u; } v; v.f = f;
  unsigned r = v.u + 0x7FFFu + ((v.u >> 16) & 1u);
  return (unsigned short)(r >> 16);
}

// CK-style global->LDS direct load, 16 bytes per lane.
// LDS dest must be wave-uniform base; HW adds lane*16.
static __device__ __forceinline__ void gload_lds16(const void* g, void* lds) {
  auto* g1 = reinterpret_cast<const __attribute__((address_space(1))) uint32_t*>(
      reinterpret_cast<uintptr_t>(g));
  auto* l3 = reinterpret_cast<__attribute__((address_space(3))) uint32_t*>(
      (uint32_t)reinterpret_cast<uintptr_t>(lds));
  __builtin_amdgcn_global_load_lds(g1, l3, 16, 0, 0);
}

// ---------------- prep kernels ----------------

__global__ void zero_meta_kernel(int* meta) {
  if (threadIdx.x < 16) meta[threadIdx.x] = 0;  // counts[6], cursor[6], spare
}

__global__ void hist_kernel(const int* __restrict__ ids, const int* __restrict__ ev2g,
                            int* __restrict__ gids, int* __restrict__ counts) {
  int i = blockIdx.x * 256 + threadIdx.x;      // grid 16x256 = 4096 exact
  int t = ids[i];
  t = t < 0 ? 0 : (t > NTYPE - 1 ? NTYPE - 1 : t);
  int g = ev2g[t];
  gids[i] = g;
  atomicAdd(&counts[g], 1);
}

__global__ void build_meta_kernel(const int* __restrict__ counts, int* __restrict__ offsets,
                                  int* __restrict__ table, int* __restrict__ ntiles) {
  if (threadIdx.x == 0) {
    int off = 0, nt = 0;
    for (int e = 0; e < NEXP; ++e) {
      offsets[e] = off;
      int c = counts[e];
      for (int t = 0; t * 128 < c; ++t) {
        int rem = c - t * 128;
        table[nt * 3 + 0] = e;
        table[nt * 3 + 1] = off + t * 128;
        table[nt * 3 + 2] = rem < 128 ? rem : 128;
        ++nt;
      }
      off += c;
    }
    offsets[NEXP] = off;
    *ntiles = nt;
  }
}

__global__ void scatter_kernel(const int* __restrict__ gids, const int* __restrict__ offsets,
                               int* __restrict__ cursor, int* __restrict__ perm) {
  int i = blockIdx.x * 256 + threadIdx.x;      // 4096 exact
  int g = gids[i];
  int pos = offsets[g] + atomicAdd(&cursor[g], 1);
  perm[pos] = i;
}

// gather x rows into permuted order, fp32 -> bf16
__global__ void xgather_kernel(const float* __restrict__ x, const int* __restrict__ perm,
                               unsigned short* __restrict__ xg) {
  int row = blockIdx.x;                        // 4096
  int t = threadIdx.x;                         // 192 threads (3 waves), 192*4 = 768
  int src = perm[row];
  float4 v = reinterpret_cast<const float4*>(x + (size_t)src * DDIM)[t];
  ushort4 o;
  o.x = f2bf(v.x); o.y = f2bf(v.y); o.z = f2bf(v.z); o.w = f2bf(v.w);
  reinterpret_cast<ushort4*>(xg + (size_t)row * DDIM)[t] = o;
}

// transpose [R][C] f32 -> [C][R] bf16, per expert (blockIdx.z)
__global__ void transconv_kernel(const float* __restrict__ src, unsigned short* __restrict__ dst,
                                 int R, int C) {
  __shared__ float tile[32][33];
  int e = blockIdx.z;
  const float* s = src + (size_t)e * R * C;
  unsigned short* d = dst + (size_t)e * R * C;
  int c0 = blockIdx.x * 32, r0 = blockIdx.y * 32;
  #pragma unroll
  for (int i = threadIdx.y; i < 32; i += 8)
    tile[i][threadIdx.x] = s[(size_t)(r0 + i) * C + c0 + threadIdx.x];
  __syncthreads();
  #pragma unroll
  for (int i = threadIdx.y; i < 32; i += 8)
    d[(size_t)(c0 + i) * R + r0 + threadIdx.x] = f2bf(tile[threadIdx.x][i]);
}

// ---------------- grouped GEMM ----------------
// A: [PADROWS][K] bf16 (permuted rows).  Bw: [E][N][K] bf16 (W^T, K contiguous).
// 128x128 tile, BK=64, 4 waves (2x2), 16x16x32 bf16 MFMA, 4x4 frags/wave.
// LDS XOR-swizzle (T2/rule #21): linear global_load_lds dest + pre-swizzled
// global source; reads apply the same XOR: byte ^= ((row&7)<<4).
template <int K, int N, int NT, bool PASS2>
__global__ __launch_bounds__(256)
void gemm_kernel(const unsigned short* __restrict__ A,
                 const unsigned short* __restrict__ Bw,
                 const float* __restrict__ bias,      // [E][N]
                 const int* __restrict__ table,
                 const int* __restrict__ ntiles,
                 const int* __restrict__ perm,
                 const float* __restrict__ x,         // [NTOK][DDIM]
                 const float* __restrict__ raw_alpha, // [E]
                 unsigned short* __restrict__ hout,   // pass1 out: [PADROWS][N] bf16
                 float* __restrict__ out)             // pass2 out: [NTOK][DDIM] f32
{
  const int mt = blockIdx.x / NT;
  const int nt = blockIdx.x % NT;
  if (mt >= *ntiles) return;
  const int e    = table[mt * 3 + 0];
  const int base = table[mt * 3 + 1];
  const int cnt  = table[mt * 3 + 2];

  __shared__ __align__(16) unsigned short As[128 * 64];
  __shared__ __align__(16) unsigned short Bs[128 * 64];

  const int tid = threadIdx.x;
  const int wave = tid >> 6, lane = tid & 63;
  const int wm = wave >> 1, wn = wave & 1;

  const unsigned short* Abase = A + (size_t)base * K;
  const unsigned short* Bbase = Bw + ((size_t)e * N + (size_t)nt * 128) * K;

  f32x4 acc[4][4];
  #pragma unroll
  for (int i = 0; i < 4; ++i)
    #pragma unroll
    for (int j = 0; j < 4; ++j) acc[i][j] = (f32x4){0.f, 0.f, 0.f, 0.f};

  // staging geometry: chunk = (wave*4+i)*64 + lane; o = chunk*16 bytes;
  // row = o>>7 (128B per row); source element pre-swizzled by ((row&7)<<4)
  int srow[4], selem[4], ldsoff[4];
  #pragma unroll
  for (int i = 0; i < 4; ++i) {
    int chunk = (wave * 4 + i) * 64 + lane;
    int o = chunk * 16;
    int row = o >> 7;
    int inb = (o & 127) ^ ((row & 7) << 4);
    srow[i] = row;
    selem[i] = inb >> 1;
    ldsoff[i] = (wave * 4 + i) * 1024;   // wave-uniform LDS byte base
  }

  for (int k0 = 0; k0 < K; k0 += 64) {
    #pragma unroll
    for (int i = 0; i < 4; ++i) {
      gload_lds16(Abase + (size_t)srow[i] * K + k0 + selem[i], (char*)As + ldsoff[i]);
      gload_lds16(Bbase + (size_t)srow[i] * K + k0 + selem[i], (char*)Bs + ldsoff[i]);
    }
    __syncthreads();   // compiler drains vmcnt(0) before barrier

    #pragma unroll
    for (int ks = 0; ks < 2; ++ks) {
      bf16x8 av[4], bv[4];
      const int kb = ks * 64 + ((lane >> 4) << 4);  // byte offset of k in row
      #pragma unroll
      for (int mi = 0; mi < 4; ++mi) {
        int row = wm * 64 + mi * 16 + (lane & 15);
        int byte = (row * 128 + kb) ^ ((row & 7) << 4);
        av[mi] = *reinterpret_cast<const bf16x8*>((const char*)As + byte);
      }
      #pragma unroll
      for (int nj = 0; nj < 4; ++nj) {
        int row = wn * 64 + nj * 16 + (lane & 15);
        int byte = (row * 128 + kb) ^ ((row & 7) << 4);
        bv[nj] = *reinterpret_cast<const bf16x8*>((const char*)Bs + byte);
      }
      #pragma unroll
      for (int mi = 0; mi < 4; ++mi)
        #pragma unroll
        for (int nj = 0; nj < 4; ++nj)
          acc[mi][nj] = __builtin_amdgcn_mfma_f32_16x16x32_bf16(av[mi], bv[nj], acc[mi][nj], 0, 0, 0);
    }
    __syncthreads();
  }

  // epilogue. C/D layout: col = lane&15, row = (lane>>4)*4 + reg  [m89/m91]
  const int col0 = nt * 128 + wn * 64;
  if (!PASS2) {
    #pragma unroll
    for (int nj = 0; nj < 4; ++nj) {
      int n = col0 + nj * 16 + (lane & 15);
      float bv = bias[e * N + n];
      #pragma unroll
      for (int mi = 0; mi < 4; ++mi) {
        int rbase = wm * 64 + mi * 16 + ((lane >> 4) << 2);
        #pragma unroll
        for (int r = 0; r < 4; ++r) {
          int row = rbase + r;
          if (row < cnt) {
            float v = acc[mi][nj][r] + bv;
            v = fmaxf(v, 0.0f);
            hout[(size_t)(base + row) * N + n] = f2bf(v);
          }
        }
      }
    }
  } else {
    float alpha = 0.05f / (1.0f + expf(-raw_alpha[e]));
    #pragma unroll
    for (int nj = 0; nj < 4; ++nj) {
      int n = col0 + nj * 16 + (lane & 15);
      float bv = bias[e * N + n];
      #pragma unroll
      for (int mi = 0; mi < 4; ++mi) {
        int rbase = wm * 64 + mi * 16 + ((lane >> 4) << 2);
        #pragma unroll
        for (int r = 0; r < 4; ++r) {
          int row = rbase + r;
          if (row < cnt) {
            int tok = perm[base + row];
            size_t oi = (size_t)tok * DDIM + n;
            out[oi] = x[oi] + alpha * (acc[mi][nj][r] + bv);
          }
        }
      }
    }
  }
}

// L2-normalize each 768-row of out in place; one wave per token
__global__ void norm_kernel(float* __restrict__ out) {
  const int wave = threadIdx.x >> 6, lane = threadIdx.x & 63;
  const int tok = (blockIdx.x << 2) + wave;       // grid 1024 x 256 -> 4096 tokens
  float4* p = reinterpret_cast<float4*>(out) + (size_t)tok * 192;
  float4 a = p[lane], b = p[lane + 64], c = p[lane + 128];
  float ss = a.x * a.x + a.y * a.y + a.z * a.z + a.w * a.w
           + b.x * b.x + b.y * b.y + b.z * b.z + b.w * b.w
           + c.x * c.x + c.y * c.y + c.z * c.z + c.w * c.w;
  #pragma unroll
  for (int off = 32; off; off >>= 1) ss += __shfl_xor(ss, off);
  const float s = 1.0f / fmaxf(sqrtf(ss), 1e-12f);
  a.x *= s; a.y *= s; a.z *= s; a.w *= s;
  b.x *= s; b.y *= s; b.z *= s; b.w *= s;
  c.x *= s; c.y *= s; c.z *= s; c.w *= s;
  p[lane] = a; p[lane + 64] = b; p[lane + 128] = c;
}

// ---------------- launch ----------------

extern "C" void kernel_launch(void* const* d_in, const int* in_sizes, int n_in,
                              void* d_out, int out_size, void* d_ws, size_t ws_size,
                              hipStream_t stream) {
  const float* x      = (const float*)d_in[0];
  const int*   ids    = (const int*)d_in[1];
  const float* W1     = (const float*)d_in[2];
  const float* b1     = (const float*)d_in[3];
  const float* W2     = (const float*)d_in[4];
  const float* b2     = (const float*)d_in[5];
  const float* ralpha = (const float*)d_in[6];
  const int*   ev2g   = (const int*)d_in[7];
  float* out = (float*)d_out;
  char* ws = (char*)d_ws;

  // workspace layout (bytes)
  unsigned short* w1t = (unsigned short*)(ws);                 // [6][1536][768] bf16
  unsigned short* w2t = (unsigned short*)(ws + 14155776);      // [6][768][1536] bf16
  unsigned short* xg  = (unsigned short*)(ws + 28311552);      // [4224][768]  bf16
  unsigned short* h   = (unsigned short*)(ws + 34799616);      // [4224][1536] bf16
  int* perm   = (int*)(ws + 47775744);
  int* gids   = (int*)(ws + 47792128);
  int* meta   = (int*)(ws + 47808512);
  int* counts  = meta;
  int* cursor  = meta + 6;
  int* offsets = meta + 12;     // [7]
  int* ntiles  = meta + 20;
  int* table   = meta + 21;     // up to 40 tiles * 3 ints

  zero_meta_kernel<<<1, 64, 0, stream>>>(meta);
  hist_kernel<<<16, 256, 0, stream>>>(ids, ev2g, gids, counts);
  build_meta_kernel<<<1, 64, 0, stream>>>(counts, offsets, table, ntiles);
  scatter_kernel<<<16, 256, 0, stream>>>(gids, offsets, cursor, perm);
  xgather_kernel<<<4096, 192, 0, stream>>>(x, perm, xg);
  transconv_kernel<<<dim3(48, 24, 6), dim3(32, 8), 0, stream>>>(W1, w1t, DDIM, HDIM);
  transconv_kernel<<<dim3(24, 48, 6), dim3(32, 8), 0, stream>>>(W2, w2t, HDIM, DDIM);
  // pass1: h = relu(xg @ W1 + b1)   M=4096 grouped, N=1536, K=768
  gemm_kernel<DDIM, HDIM, 12, false><<<40 * 12, 256, 0, stream>>>(
      xg, w1t, b1, table, ntiles, perm, x, ralpha, h, out);
  // pass2: out = x + alpha*(h @ W2 + b2)  M=4096 grouped, N=768, K=1536
  gemm_kernel<HDIM, DDIM, 6, true><<<40 * 6, 256, 0, stream>>>(
      h, w2t, b2, table, ntiles, perm, x, ralpha, nullptr, out);
  norm_kernel<<<1024, 256, 0, stream>>>(out);
}

// Round 2
// 192.719 us; speedup vs baseline: 1.4086x; 1.4086x over previous
//
#include <hip/hip_runtime.h>
#include <hip/hip_bf16.h>
#include <stdint.h>

#define NTOK 4096
#define DDIM 768
#define HDIM 1536
#define NEXP 6
#define NTYPE 32
#define PADROWS 4224

typedef __bf16 bf16x8 __attribute__((ext_vector_type(8)));
typedef float f32x4 __attribute__((ext_vector_type(4)));

static __device__ __forceinline__ unsigned short f2bf(float f) {
  union { float f; unsigned u; } v; v.f = f;
  unsigned r = v.u + 0x7FFFu + ((v.u >> 16) & 1u);
  return (unsigned short)(r >> 16);
}

static __device__ __forceinline__ void gload_lds16(const void* g, void* lds) {
  auto* g1 = reinterpret_cast<const __attribute__((address_space(1))) uint32_t*>(
      reinterpret_cast<uintptr_t>(g));
  auto* l3 = reinterpret_cast<__attribute__((address_space(3))) uint32_t*>(
      (uint32_t)reinterpret_cast<uintptr_t>(lds));
  __builtin_amdgcn_global_load_lds(g1, l3, 16, 0, 0);
}

// ---------------- bucketing: one block does hist + offsets + tile table + scatter
__global__ void bucket_kernel(const int* __restrict__ ids, const int* __restrict__ ev2g,
                              int* __restrict__ perm, int* __restrict__ meta) {
  __shared__ int s_ev2g[NTYPE];
  __shared__ int s_cnt[NEXP];
  __shared__ int s_off[NEXP];
  __shared__ int s_cur[NEXP];
  const int tid = threadIdx.x;                   // 1024 threads
  if (tid < NTYPE) s_ev2g[tid] = ev2g[tid];
  if (tid < NEXP) { s_cnt[tid] = 0; s_cur[tid] = 0; }
  __syncthreads();
  int g[4];
  #pragma unroll
  for (int i = 0; i < 4; ++i) {
    int idx = tid * 4 + i;
    int t = ids[idx];
    t = t < 0 ? 0 : (t > NTYPE - 1 ? NTYPE - 1 : t);
    g[i] = s_ev2g[t];
    atomicAdd(&s_cnt[g[i]], 1);
  }
  __syncthreads();
  if (tid == 0) {
    int off = 0, nt = 0;
    int* table = meta + 21;
    for (int e = 0; e < NEXP; ++e) {
      s_off[e] = off;
      int c = s_cnt[e];
      for (int t = 0; t * 128 < c; ++t) {
        int rem = c - t * 128;
        table[nt * 3 + 0] = e;
        table[nt * 3 + 1] = off + t * 128;
        table[nt * 3 + 2] = rem < 128 ? rem : 128;
        ++nt;
      }
      off += c;
    }
    meta[20] = nt;
  }
  __syncthreads();
  #pragma unroll
  for (int i = 0; i < 4; ++i) {
    int idx = tid * 4 + i;
    int pos = s_off[g[i]] + atomicAdd(&s_cur[g[i]], 1);
    perm[pos] = idx;
  }
}

// gather x rows into permuted order, fp32 -> bf16
__global__ void xgather_kernel(const float* __restrict__ x, const int* __restrict__ perm,
                               unsigned short* __restrict__ xg) {
  int row = blockIdx.x;                        // 4096
  int t = threadIdx.x;                         // 192 threads
  int src = perm[row];
  float4 v = reinterpret_cast<const float4*>(x + (size_t)src * DDIM)[t];
  ushort4 o;
  o.x = f2bf(v.x); o.y = f2bf(v.y); o.z = f2bf(v.z); o.w = f2bf(v.w);
  reinterpret_cast<ushort4*>(xg + (size_t)row * DDIM)[t] = o;
}

// transpose [R][C] f32 -> [C][R] bf16, per expert (blockIdx.z)
__global__ void transconv_kernel(const float* __restrict__ src, unsigned short* __restrict__ dst,
                                 int R, int C) {
  __shared__ float tile[32][33];
  int e = blockIdx.z;
  const float* s = src + (size_t)e * R * C;
  unsigned short* d = dst + (size_t)e * R * C;
  int c0 = blockIdx.x * 32, r0 = blockIdx.y * 32;
  #pragma unroll
  for (int i = threadIdx.y; i < 32; i += 8)
    tile[i][threadIdx.x] = s[(size_t)(r0 + i) * C + c0 + threadIdx.x];
  __syncthreads();
  #pragma unroll
  for (int i = threadIdx.y; i < 32; i += 8)
    d[(size_t)(c0 + i) * R + r0 + threadIdx.x] = f2bf(tile[threadIdx.x][i]);
}

// ---------------- grouped GEMM, 8 waves, 2-phase double-buffered pipeline ----------------
// A: [PADROWS][K] bf16 permuted rows. Bw: [E][NT*BN][K] bf16 (W^T, K contiguous).
// BM=128 x BN tile, BK=64, 512 threads (WMW x WNW wave grid), 16x16x32 bf16 MFMA.
// LDS XOR-swizzle via pre-swizzled global source (rule #21); reads apply same XOR.
template <int K, int BN, int NT, int WMW, int WNW, bool PASS2>
__global__ __launch_bounds__(512, 4)
void gemm_kernel(const unsigned short* __restrict__ A,
                 const unsigned short* __restrict__ Bw,
                 const float* __restrict__ bias,      // [E][NT*BN]
                 const int* __restrict__ meta,
                 const int* __restrict__ perm,
                 const float* __restrict__ x,         // [NTOK][DDIM]
                 const float* __restrict__ raw_alpha, // [E]
                 unsigned short* __restrict__ hout,   // pass1: [PADROWS][HDIM]
                 float* __restrict__ out)             // pass2: [NTOK][DDIM]
{
  constexpr int BM = 128;
  constexpr int NDIM = NT * BN;
  constexpr int MFR = BM / (16 * WMW);
  constexpr int NFR = BN / (16 * WNW);
  constexpr int NK = K / 64;
  constexpr int ACH = BM / 64;   // A 16B-chunks per thread per K-tile
  constexpr int BCH = BN / 64;
  static_assert(WMW * WNW == 8, "8 waves");

  // XCD-chunked bijective swizzle (nwg = 40*NT = 480, divisible by 8)
  const int nwg = 40 * NT;
  const int q = nwg >> 3;
  const int vid = (blockIdx.x & 7) * q + (blockIdx.x >> 3);
  const int nt = vid / 40;       // nt-major: neighbors share B-panel -> same-XCD L2
  const int mt = vid % 40;
  if (mt >= meta[20]) return;
  const int* table = meta + 21;
  const int e = table[mt * 3 + 0], base = table[mt * 3 + 1], cnt = table[mt * 3 + 2];

  __shared__ __align__(16) unsigned short As[2][BM * 64];
  __shared__ __align__(16) unsigned short Bs[2][BN * 64];

  const int tid = threadIdx.x;
  const int wave = tid >> 6, lane = tid & 63;
  const int wm = wave / WNW, wn = wave % WNW;

  const unsigned short* Abase = A + (size_t)base * K;
  const unsigned short* Bbase = Bw + ((size_t)e * NDIM + (size_t)nt * BN) * K;

  f32x4 acc[MFR][NFR];
  #pragma unroll
  for (int i = 0; i < MFR; ++i)
    #pragma unroll
    for (int j = 0; j < NFR; ++j) acc[i][j] = (f32x4){0.f, 0.f, 0.f, 0.f};

  // staging descriptors: chunk = i*512 + tid; 16B per chunk; 128B per LDS row
  int aRow[ACH], aElem[ACH], aLds[ACH];
  #pragma unroll
  for (int i = 0; i < ACH; ++i) {
    int chunk = i * 512 + tid;
    int o = chunk * 16;
    int row = o >> 7;
    int inb = (o & 127) ^ ((row & 7) << 4);
    aRow[i] = row; aElem[i] = inb >> 1;
    aLds[i] = (i * 512 + wave * 64) * 16;        // wave-uniform dest base
  }
  int bRow[BCH], bElem[BCH], bLds[BCH];
  #pragma unroll
  for (int i = 0; i < BCH; ++i) {
    int chunk = i * 512 + tid;
    int o = chunk * 16;
    int row = o >> 7;
    int inb = (o & 127) ^ ((row & 7) << 4);
    bRow[i] = row; bElem[i] = inb >> 1;
    bLds[i] = (i * 512 + wave * 64) * 16;
  }

  // prologue: stage tile 0
  #pragma unroll
  for (int i = 0; i < ACH; ++i)
    gload_lds16(Abase + (size_t)aRow[i] * K + aElem[i], (char*)As[0] + aLds[i]);
  #pragma unroll
  for (int i = 0; i < BCH; ++i)
    gload_lds16(Bbase + (size_t)bRow[i] * K + bElem[i], (char*)Bs[0] + bLds[i]);
  __syncthreads();

  int cur = 0;
  for (int kt = 0; kt < NK; ++kt) {
    if (kt + 1 < NK) {               // issue next-tile loads BEFORE compute
      const int k0 = (kt + 1) * 64;
      #pragma unroll
      for (int i = 0; i < ACH; ++i)
        gload_lds16(Abase + (size_t)aRow[i] * K + k0 + aElem[i], (char*)As[cur ^ 1] + aLds[i]);
      #pragma unroll
      for (int i = 0; i < BCH; ++i)
        gload_lds16(Bbase + (size_t)bRow[i] * K + k0 + bElem[i], (char*)Bs[cur ^ 1] + bLds[i]);
    }
    #pragma unroll
    for (int ks = 0; ks < 2; ++ks) {
      bf16x8 av[MFR], bv[NFR];
      const int kb = ks * 64 + ((lane >> 4) << 4);
      #pragma unroll
      for (int mi = 0; mi < MFR; ++mi) {
        int row = wm * (MFR * 16) + mi * 16 + (lane & 15);
        int byte = (row * 128 + kb) ^ ((row & 7) << 4);
        av[mi] = *reinterpret_cast<const bf16x8*>((const char*)As[cur] + byte);
      }
      #pragma unroll
      for (int nj = 0; nj < NFR; ++nj) {
        int row = wn * (NFR * 16) + nj * 16 + (lane & 15);
        int byte = (row * 128 + kb) ^ ((row & 7) << 4);
        bv[nj] = *reinterpret_cast<const bf16x8*>((const char*)Bs[cur] + byte);
      }
      #pragma unroll
      for (int mi = 0; mi < MFR; ++mi)
        #pragma unroll
        for (int nj = 0; nj < NFR; ++nj)
          acc[mi][nj] = __builtin_amdgcn_mfma_f32_16x16x32_bf16(av[mi], bv[nj], acc[mi][nj], 0, 0, 0);
    }
    __syncthreads();                 // drains vmcnt (next tile landed) + protects buffer reuse
    cur ^= 1;
  }

  // epilogue. C/D layout: col = lane&15, row = (lane>>4)*4 + reg
  const int col0 = nt * BN + wn * (NFR * 16);
  if constexpr (!PASS2) {
    #pragma unroll
    for (int nj = 0; nj < NFR; ++nj) {
      int n = col0 + nj * 16 + (lane & 15);
      float bv = bias[e * NDIM + n];
      #pragma unroll
      for (int mi = 0; mi < MFR; ++mi) {
        int rbase = wm * (MFR * 16) + mi * 16 + ((lane >> 4) << 2);
        #pragma unroll
        for (int r = 0; r < 4; ++r) {
          int row = rbase + r;
          if (row < cnt) {
            float v = fmaxf(acc[mi][nj][r] + bv, 0.0f);
            hout[(size_t)(base + row) * NDIM + n] = f2bf(v);
          }
        }
      }
    }
  } else {
    float alpha = 0.05f / (1.0f + expf(-raw_alpha[e]));
    #pragma unroll
    for (int nj = 0; nj < NFR; ++nj) {
      int n = col0 + nj * 16 + (lane & 15);
      float bv = bias[e * NDIM + n];
      #pragma unroll
      for (int mi = 0; mi < MFR; ++mi) {
        int rbase = wm * (MFR * 16) + mi * 16 + ((lane >> 4) << 2);
        #pragma unroll
        for (int r = 0; r < 4; ++r) {
          int row = rbase + r;
          if (row < cnt) {
            int tok = perm[base + row];
            size_t oi = (size_t)tok * DDIM + n;
            out[oi] = x[oi] + alpha * (acc[mi][nj][r] + bv);
          }
        }
      }
    }
  }
}

// L2-normalize each 768-row of out in place; one wave per token
__global__ void norm_kernel(float* __restrict__ out) {
  const int wave = threadIdx.x >> 6, lane = threadIdx.x & 63;
  const int tok = (blockIdx.x << 2) + wave;
  float4* p = reinterpret_cast<float4*>(out) + (size_t)tok * 192;
  float4 a = p[lane], b = p[lane + 64], c = p[lane + 128];
  float ss = a.x * a.x + a.y * a.y + a.z * a.z + a.w * a.w
           + b.x * b.x + b.y * b.y + b.z * b.z + b.w * b.w
           + c.x * c.x + c.y * c.y + c.z * c.z + c.w * c.w;
  #pragma unroll
  for (int off = 32; off; off >>= 1) ss += __shfl_xor(ss, off);
  const float s = 1.0f / fmaxf(sqrtf(ss), 1e-12f);
  a.x *= s; a.y *= s; a.z *= s; a.w *= s;
  b.x *= s; b.y *= s; b.z *= s; b.w *= s;
  c.x *= s; c.y *= s; c.z *= s; c.w *= s;
  p[lane] = a; p[lane + 64] = b; p[lane + 128] = c;
}

// ---------------- launch ----------------

extern "C" void kernel_launch(void* const* d_in, const int* in_sizes, int n_in,
                              void* d_out, int out_size, void* d_ws, size_t ws_size,
                              hipStream_t stream) {
  const float* x      = (const float*)d_in[0];
  const int*   ids    = (const int*)d_in[1];
  const float* W1     = (const float*)d_in[2];
  const float* b1     = (const float*)d_in[3];
  const float* W2     = (const float*)d_in[4];
  const float* b2     = (const float*)d_in[5];
  const float* ralpha = (const float*)d_in[6];
  const int*   ev2g   = (const int*)d_in[7];
  float* out = (float*)d_out;
  char* ws = (char*)d_ws;

  unsigned short* w1t = (unsigned short*)(ws);                 // [6][1536][768] bf16
  unsigned short* w2t = (unsigned short*)(ws + 14155776);      // [6][768][1536] bf16
  unsigned short* xg  = (unsigned short*)(ws + 28311552);      // [4224][768]  bf16
  unsigned short* h   = (unsigned short*)(ws + 34799616);      // [4224][1536] bf16
  int* perm = (int*)(ws + 47775744);
  int* meta = (int*)(ws + 47808512);

  bucket_kernel<<<1, 1024, 0, stream>>>(ids, ev2g, perm, meta);
  transconv_kernel<<<dim3(48, 24, 6), dim3(32, 8), 0, stream>>>(W1, w1t, DDIM, HDIM);
  transconv_kernel<<<dim3(24, 48, 6), dim3(32, 8), 0, stream>>>(W2, w2t, HDIM, DDIM);
  xgather_kernel<<<4096, 192, 0, stream>>>(x, perm, xg);
  // pass1: h = relu(xg @ W1 + b1)   M=4096 grouped, N=1536, K=768
  gemm_kernel<DDIM, 128, 12, 2, 4, false><<<480, 512, 0, stream>>>(
      xg, w1t, b1, meta, perm, x, ralpha, h, out);
  // pass2: out = x + alpha*(h @ W2 + b2)  M=4096 grouped, N=768, K=1536
  gemm_kernel<HDIM, 64, 12, 4, 2, true><<<480, 512, 0, stream>>>(
      h, w2t, b2, meta, perm, x, ralpha, nullptr, out);
  norm_kernel<<<1024, 256, 0, stream>>>(out);
}

// Round 5
// 178.298 us; speedup vs baseline: 1.5226x; 1.0809x over previous
//
#include <hip/hip_runtime.h>
#include <hip/hip_bf16.h>
#include <stdint.h>

#define NTOK 4096
#define DDIM 768
#define HDIM 1536
#define NEXP 6
#define NTYPE 32
#define PADROWS 4224

typedef __bf16 bf16x8 __attribute__((ext_vector_type(8)));
typedef float f32x4 __attribute__((ext_vector_type(4)));

static __device__ __forceinline__ unsigned short f2bf(float f) {
  union { float f; unsigned u; } v; v.f = f;
  unsigned r = v.u + 0x7FFFu + ((v.u >> 16) & 1u);
  return (unsigned short)(r >> 16);
}

static __device__ __forceinline__ void gload_lds16(const void* g, void* lds) {
  auto* g1 = reinterpret_cast<const __attribute__((address_space(1))) uint32_t*>(
      reinterpret_cast<uintptr_t>(g));
  auto* l3 = reinterpret_cast<__attribute__((address_space(3))) uint32_t*>(
      (uint32_t)reinterpret_cast<uintptr_t>(lds));
  __builtin_amdgcn_global_load_lds(g1, l3, 16, 0, 0);
}

// ---------------- bucketing: one block does hist + offsets + tile table + scatter
__global__ void bucket_kernel(const int* __restrict__ ids, const int* __restrict__ ev2g,
                              int* __restrict__ perm, int* __restrict__ meta) {
  __shared__ int s_ev2g[NTYPE];
  __shared__ int s_cnt[NEXP];
  __shared__ int s_off[NEXP];
  __shared__ int s_cur[NEXP];
  const int tid = threadIdx.x;                   // 1024 threads
  if (tid < NTYPE) s_ev2g[tid] = ev2g[tid];
  if (tid < NEXP) { s_cnt[tid] = 0; s_cur[tid] = 0; }
  __syncthreads();
  int g[4];
  #pragma unroll
  for (int i = 0; i < 4; ++i) {
    int idx = tid * 4 + i;
    int t = ids[idx];
    t = t < 0 ? 0 : (t > NTYPE - 1 ? NTYPE - 1 : t);
    g[i] = s_ev2g[t];
    atomicAdd(&s_cnt[g[i]], 1);
  }
  __syncthreads();
  if (tid == 0) {
    int off = 0, nt = 0;
    int* table = meta + 21;
    for (int e = 0; e < NEXP; ++e) {
      s_off[e] = off;
      int c = s_cnt[e];
      for (int t = 0; t * 128 < c; ++t) {
        int rem = c - t * 128;
        table[nt * 3 + 0] = e;
        table[nt * 3 + 1] = off + t * 128;
        table[nt * 3 + 2] = rem < 128 ? rem : 128;
        ++nt;
      }
      off += c;
    }
    meta[20] = nt;
  }
  __syncthreads();
  #pragma unroll
  for (int i = 0; i < 4; ++i) {
    int idx = tid * 4 + i;
    int pos = s_off[g[i]] + atomicAdd(&s_cur[g[i]], 1);
    perm[pos] = idx;
  }
}

// gather x rows into permuted order, fp32 -> bf16
__global__ void xgather_kernel(const float* __restrict__ x, const int* __restrict__ perm,
                               unsigned short* __restrict__ xg) {
  int row = blockIdx.x;                        // 4096
  int t = threadIdx.x;                         // 192 threads
  int src = perm[row];
  float4 v = reinterpret_cast<const float4*>(x + (size_t)src * DDIM)[t];
  ushort4 o;
  o.x = f2bf(v.x); o.y = f2bf(v.y); o.z = f2bf(v.z); o.w = f2bf(v.w);
  reinterpret_cast<ushort4*>(xg + (size_t)row * DDIM)[t] = o;
}

// ---------------- fused weight transpose+convert ----------------
// z<6: W1 expert z  [768][1536] f32 -> w1t [1536][768] bf16
// z>=6: W2 expert z-6 [1536][768] f32 -> w2t [768][1536] bf16
// 64x64 fp32 tile, 256 threads. float4 row reads (256B/row seg), LDS [64][65]
// (max 2-way bank alias = free), dense uint4 bf16 writes (16B/lane).
__global__ __launch_bounds__(256)
void transpose_kernel(const float* __restrict__ W1, const float* __restrict__ W2,
                      unsigned short* __restrict__ w1t, unsigned short* __restrict__ w2t) {
  __shared__ float tile[64][65];
  const int z = blockIdx.z;
  const float* src;
  unsigned short* dst;
  int R, C, bx, by;
  if (z < 6) {
    src = W1 + (size_t)z * 768 * 1536; dst = w1t + (size_t)z * 768 * 1536;
    R = 768; C = 1536; bx = blockIdx.x; by = blockIdx.y;     // bx<24, by<12
  } else {
    src = W2 + (size_t)(z - 6) * 768 * 1536; dst = w2t + (size_t)(z - 6) * 768 * 1536;
    R = 1536; C = 768; bx = blockIdx.y; by = blockIdx.x;     // bx<12, by<24
  }
  const int r0 = by * 64, c0 = bx * 64;
  const int t = threadIdx.x;
  const int lr = t >> 4;           // 0..15
  const int lc = (t & 15) << 2;    // 0..60 step 4
  #pragma unroll
  for (int i = 0; i < 4; ++i) {
    float4 v = *reinterpret_cast<const float4*>(src + (size_t)(r0 + i * 16 + lr) * C + c0 + lc);
    tile[i * 16 + lr][lc]     = v.x;
    tile[i * 16 + lr][lc + 1] = v.y;
    tile[i * 16 + lr][lc + 2] = v.z;
    tile[i * 16 + lr][lc + 3] = v.w;
  }
  __syncthreads();
  const int l8 = (t & 7) << 3;     // 0..56 step 8 (source-row chunk)
  #pragma unroll
  for (int p = 0; p < 2; ++p) {
    int j = p * 32 + (t >> 3);     // out-row within tile (= source col)
    union { unsigned short u[8]; uint4 v; } pk;
    #pragma unroll
    for (int k = 0; k < 8; ++k) pk.u[k] = f2bf(tile[l8 + k][j]);
    *reinterpret_cast<uint4*>(dst + (size_t)(c0 + j) * R + r0 + l8) = pk.v;
  }
}

// ---------------- grouped GEMM, 8 waves, 2-phase double-buffered pipeline ----------------
// A: [PADROWS][K] bf16 permuted rows. Bw: [E][NT*BN][K] bf16 (W^T, K contiguous).
// BM=128 x BN tile, BK=64, 512 threads (WMW x WNW wave grid), 16x16x32 bf16 MFMA.
// LDS XOR-swizzle via pre-swizzled global source (rule #21); reads apply same XOR.
template <int K, int BN, int NT, int WMW, int WNW, bool PASS2>
__global__ __launch_bounds__(512, 4)
void gemm_kernel(const unsigned short* __restrict__ A,
                 const unsigned short* __restrict__ Bw,
                 const float* __restrict__ bias,      // [E][NT*BN]
                 const int* __restrict__ meta,
                 const int* __restrict__ perm,
                 const float* __restrict__ x,         // [NTOK][DDIM]
                 const float* __restrict__ raw_alpha, // [E]
                 unsigned short* __restrict__ hout,   // pass1: [PADROWS][HDIM]
                 float* __restrict__ out)             // pass2: [NTOK][DDIM]
{
  constexpr int BM = 128;
  constexpr int NDIM = NT * BN;
  constexpr int MFR = BM / (16 * WMW);
  constexpr int NFR = BN / (16 * WNW);
  constexpr int NK = K / 64;
  constexpr int ACH = BM / 64;
  constexpr int BCH = BN / 64;
  static_assert(WMW * WNW == 8, "8 waves");

  // XCD-chunked bijective swizzle (nwg = 40*NT = 480, divisible by 8)
  const int nwg = 40 * NT;
  const int q = nwg >> 3;
  const int vid = (blockIdx.x & 7) * q + (blockIdx.x >> 3);
  const int nt = vid / 40;       // nt-major: neighbors share B-panel -> same-XCD L2
  const int mt = vid % 40;
  if (mt >= meta[20]) return;
  const int* table = meta + 21;
  const int e = table[mt * 3 + 0], base = table[mt * 3 + 1], cnt = table[mt * 3 + 2];

  __shared__ __align__(16) unsigned short As[2][BM * 64];
  __shared__ __align__(16) unsigned short Bs[2][BN * 64];

  const int tid = threadIdx.x;
  const int wave = tid >> 6, lane = tid & 63;
  const int wm = wave / WNW, wn = wave % WNW;

  const unsigned short* Abase = A + (size_t)base * K;
  const unsigned short* Bbase = Bw + ((size_t)e * NDIM + (size_t)nt * BN) * K;

  f32x4 acc[MFR][NFR];
  #pragma unroll
  for (int i = 0; i < MFR; ++i)
    #pragma unroll
    for (int j = 0; j < NFR; ++j) acc[i][j] = (f32x4){0.f, 0.f, 0.f, 0.f};

  int aRow[ACH], aElem[ACH], aLds[ACH];
  #pragma unroll
  for (int i = 0; i < ACH; ++i) {
    int chunk = i * 512 + tid;
    int o = chunk * 16;
    int row = o >> 7;
    int inb = (o & 127) ^ ((row & 7) << 4);
    aRow[i] = row; aElem[i] = inb >> 1;
    aLds[i] = (i * 512 + wave * 64) * 16;
  }
  int bRow[BCH], bElem[BCH], bLds[BCH];
  #pragma unroll
  for (int i = 0; i < BCH; ++i) {
    int chunk = i * 512 + tid;
    int o = chunk * 16;
    int row = o >> 7;
    int inb = (o & 127) ^ ((row & 7) << 4);
    bRow[i] = row; bElem[i] = inb >> 1;
    bLds[i] = (i * 512 + wave * 64) * 16;
  }

  // prologue: stage tile 0
  #pragma unroll
  for (int i = 0; i < ACH; ++i)
    gload_lds16(Abase + (size_t)aRow[i] * K + aElem[i], (char*)As[0] + aLds[i]);
  #pragma unroll
  for (int i = 0; i < BCH; ++i)
    gload_lds16(Bbase + (size_t)bRow[i] * K + bElem[i], (char*)Bs[0] + bLds[i]);
  __syncthreads();

  int cur = 0;
  for (int kt = 0; kt < NK; ++kt) {
    if (kt + 1 < NK) {               // issue next-tile loads BEFORE compute
      const int k0 = (kt + 1) * 64;
      #pragma unroll
      for (int i = 0; i < ACH; ++i)
        gload_lds16(Abase + (size_t)aRow[i] * K + k0 + aElem[i], (char*)As[cur ^ 1] + aLds[i]);
      #pragma unroll
      for (int i = 0; i < BCH; ++i)
        gload_lds16(Bbase + (size_t)bRow[i] * K + k0 + bElem[i], (char*)Bs[cur ^ 1] + bLds[i]);
    }
    #pragma unroll
    for (int ks = 0; ks < 2; ++ks) {
      bf16x8 av[MFR], bv[NFR];
      const int kb = ks * 64 + ((lane >> 4) << 4);
      #pragma unroll
      for (int mi = 0; mi < MFR; ++mi) {
        int row = wm * (MFR * 16) + mi * 16 + (lane & 15);
        int byte = (row * 128 + kb) ^ ((row & 7) << 4);
        av[mi] = *reinterpret_cast<const bf16x8*>((const char*)As[cur] + byte);
      }
      #pragma unroll
      for (int nj = 0; nj < NFR; ++nj) {
        int row = wn * (NFR * 16) + nj * 16 + (lane & 15);
        int byte = (row * 128 + kb) ^ ((row & 7) << 4);
        bv[nj] = *reinterpret_cast<const bf16x8*>((const char*)Bs[cur] + byte);
      }
      #pragma unroll
      for (int mi = 0; mi < MFR; ++mi)
        #pragma unroll
        for (int nj = 0; nj < NFR; ++nj)
          acc[mi][nj] = __builtin_amdgcn_mfma_f32_16x16x32_bf16(av[mi], bv[nj], acc[mi][nj], 0, 0, 0);
    }
    __syncthreads();
    cur ^= 1;
  }

  // epilogue. C/D layout: col = lane&15, row = (lane>>4)*4 + reg
  const int col0 = nt * BN + wn * (NFR * 16);
  if constexpr (!PASS2) {
    #pragma unroll
    for (int nj = 0; nj < NFR; ++nj) {
      int n = col0 + nj * 16 + (lane & 15);
      float bv = bias[e * NDIM + n];
      #pragma unroll
      for (int mi = 0; mi < MFR; ++mi) {
        int rbase = wm * (MFR * 16) + mi * 16 + ((lane >> 4) << 2);
        #pragma unroll
        for (int r = 0; r < 4; ++r) {
          int row = rbase + r;
          if (row < cnt) {
            float v = fmaxf(acc[mi][nj][r] + bv, 0.0f);
            hout[(size_t)(base + row) * NDIM + n] = f2bf(v);
          }
        }
      }
    }
  } else {
    float alpha = 0.05f / (1.0f + expf(-raw_alpha[e]));
    #pragma unroll
    for (int nj = 0; nj < NFR; ++nj) {
      int n = col0 + nj * 16 + (lane & 15);
      float bv = bias[e * NDIM + n];
      #pragma unroll
      for (int mi = 0; mi < MFR; ++mi) {
        int rbase = wm * (MFR * 16) + mi * 16 + ((lane >> 4) << 2);
        #pragma unroll
        for (int r = 0; r < 4; ++r) {
          int row = rbase + r;
          if (row < cnt) {
            int tok = perm[base + row];
            size_t oi = (size_t)tok * DDIM + n;
            out[oi] = x[oi] + alpha * (acc[mi][nj][r] + bv);
          }
        }
      }
    }
  }
}

// L2-normalize each 768-row of out in place; one wave per token
__global__ void norm_kernel(float* __restrict__ out) {
  const int wave = threadIdx.x >> 6, lane = threadIdx.x & 63;
  const int tok = (blockIdx.x << 2) + wave;
  float4* p = reinterpret_cast<float4*>(out) + (size_t)tok * 192;
  float4 a = p[lane], b = p[lane + 64], c = p[lane + 128];
  float ss = a.x * a.x + a.y * a.y + a.z * a.z + a.w * a.w
           + b.x * b.x + b.y * b.y + b.z * b.z + b.w * b.w
           + c.x * c.x + c.y * c.y + c.z * c.z + c.w * c.w;
  #pragma unroll
  for (int off = 32; off; off >>= 1) ss += __shfl_xor(ss, off);
  const float s = 1.0f / fmaxf(sqrtf(ss), 1e-12f);
  a.x *= s; a.y *= s; a.z *= s; a.w *= s;
  b.x *= s; b.y *= s; b.z *= s; b.w *= s;
  c.x *= s; c.y *= s; c.z *= s; c.w *= s;
  p[lane] = a; p[lane + 64] = b; p[lane + 128] = c;
}

// ---------------- launch ----------------

extern "C" void kernel_launch(void* const* d_in, const int* in_sizes, int n_in,
                              void* d_out, int out_size, void* d_ws, size_t ws_size,
                              hipStream_t stream) {
  const float* x      = (const float*)d_in[0];
  const int*   ids    = (const int*)d_in[1];
  const float* W1     = (const float*)d_in[2];
  const float* b1     = (const float*)d_in[3];
  const float* W2     = (const float*)d_in[4];
  const float* b2     = (const float*)d_in[5];
  const float* ralpha = (const float*)d_in[6];
  const int*   ev2g   = (const int*)d_in[7];
  float* out = (float*)d_out;
  char* ws = (char*)d_ws;

  unsigned short* w1t = (unsigned short*)(ws);                 // [6][1536][768] bf16
  unsigned short* w2t = (unsigned short*)(ws + 14155776);      // [6][768][1536] bf16
  unsigned short* xg  = (unsigned short*)(ws + 28311552);      // [4224][768]  bf16
  unsigned short* h   = (unsigned short*)(ws + 34799616);      // [4224][1536] bf16
  int* perm = (int*)(ws + 47775744);
  int* meta = (int*)(ws + 47808512);

  bucket_kernel<<<1, 1024, 0, stream>>>(ids, ev2g, perm, meta);
  transpose_kernel<<<dim3(24, 12, 12), 256, 0, stream>>>(W1, W2, w1t, w2t);
  xgather_kernel<<<4096, 192, 0, stream>>>(x, perm, xg);
  // pass1: h = relu(xg @ W1 + b1)   M=4096 grouped, N=1536, K=768
  gemm_kernel<DDIM, 128, 12, 2, 4, false><<<480, 512, 0, stream>>>(
      xg, w1t, b1, meta, perm, x, ralpha, h, out);
  // pass2: out = x + alpha*(h @ W2 + b2)  M=4096 grouped, N=768, K=1536
  gemm_kernel<HDIM, 64, 12, 4, 2, true><<<480, 512, 0, stream>>>(
      h, w2t, b2, meta, perm, x, ralpha, nullptr, out);
  norm_kernel<<<1024, 256, 0, stream>>>(out);
}